// Round 1
// baseline (339.913 us; speedup 1.0000x reference)
//
#include <hip/hip_runtime.h>
#include <hip/hip_bf16.h>
#include <cstdint>
#include <cstddef>

using bf16 = __hip_bfloat16;
using short8 = __attribute__((ext_vector_type(8))) short;
using f32x4  = __attribute__((ext_vector_type(4))) float;

#define DEVI __device__ __forceinline__

// async global->LDS, 16B per lane. LDS dest is wave-uniform base + lane*16.
DEVI void async_ld16(const void* g, void* l) {
  __builtin_amdgcn_global_load_lds(
      (const __attribute__((address_space(1))) unsigned int*)g,
      (__attribute__((address_space(3))) unsigned int*)l, 16, 0, 0);
}

// ---------------------------------------------------------------- cvt f32->bf16
__global__ void cvt_f32_bf16(const float* __restrict__ in, bf16* __restrict__ out, int n4) {
  int i = blockIdx.x * blockDim.x + threadIdx.x;
  if (i >= n4) return;
  float4 v = ((const float4*)in)[i];
  union { bf16 h[4]; ushort4 u; } o;
  o.h[0] = __float2bfloat16(v.x);
  o.h[1] = __float2bfloat16(v.y);
  o.h[2] = __float2bfloat16(v.z);
  o.h[3] = __float2bfloat16(v.w);
  ((ushort4*)out)[i] = o.u;
}

// ------------------------------------------- transpose + cvt: in[K][N] -> out[N][K]
__global__ __launch_bounds__(256) void transpose_cvt(
    const float* __restrict__ in, bf16* __restrict__ out, int K, int N) {
  __shared__ float tile[32][33];
  int n0 = blockIdx.x * 32, k0 = blockIdx.y * 32;
  int tx = threadIdx.x & 31, ty = threadIdx.x >> 5;  // 32 x 8
#pragma unroll
  for (int i = 0; i < 32; i += 8)
    tile[ty + i][tx] = in[(size_t)(k0 + ty + i) * N + n0 + tx];
  __syncthreads();
#pragma unroll
  for (int i = 0; i < 32; i += 8)
    out[(size_t)(n0 + ty + i) * K + k0 + tx] = __float2bfloat16(tile[tx][ty + i]);
}

// ---------------------------------------------------------------- rope table
__global__ void rope_tab(float2* __restrict__ tab) {
  int t = blockIdx.x, i = threadIdx.x;  // T blocks x 64 threads
  float ex = -2.f * (float)i * (1.f / 128.f);
  float theta = exp2f(ex * 19.9315685693241741f);  // log2(1e6)
  float f = (float)t * theta;
  float sv, cv;
  sincosf(f, &sv, &cv);
  tab[t * 64 + i] = make_float2(cv, sv);
}

// ------------------------------------------------- GEMM: C[M][N] = A[M][K] * Bt[N][K]^T
// 128x128 tile, BK=64, 4 waves (2x2), 16x16x32 bf16 MFMA.
// LDS tiles row-major [128][64] bf16 (128B rows), XOR-swizzled byte ^= (row&7)<<4.
template <bool OUT_F32>
__global__ __launch_bounds__(256) void gemm_bt(
    const bf16* __restrict__ A, const bf16* __restrict__ Bt,
    void* __restrict__ Cv, int M, int N, int K) {
  __shared__ alignas(16) bf16 As[128 * 64];
  __shared__ alignas(16) bf16 Bs[128 * 64];
  const int tid = threadIdx.x, lane = tid & 63, w = tid >> 6;
  const int wm = w >> 1, wn = w & 1;
  const int m0 = blockIdx.y * 128, n0 = blockIdx.x * 128;
  f32x4 acc[4][4] = {};

  const int srow = lane >> 3;          // row within 8-row slab
  const int scb  = (lane & 7) * 16;    // linear col byte

  for (int kt = 0; kt < K; kt += 64) {
#pragma unroll
    for (int i = 0; i < 4; i++) {
      int row = w * 32 + i * 8 + srow;
      int src_cb = scb ^ ((row & 7) << 4);  // pre-swizzled source (rule #21)
      async_ld16((const char*)(A  + (size_t)(m0 + row) * K + kt) + src_cb,
                 (char*)As + w * 4096 + i * 1024);
      async_ld16((const char*)(Bt + (size_t)(n0 + row) * K + kt) + src_cb,
                 (char*)Bs + w * 4096 + i * 1024);
    }
    __syncthreads();
#pragma unroll
    for (int ks = 0; ks < 2; ks++) {
      short8 af[4], bfr[4];
#pragma unroll
      for (int mi = 0; mi < 4; mi++) {
        int row = wm * 64 + mi * 16 + (lane & 15);
        int cb = (ks * 64 + (lane >> 4) * 16) ^ ((row & 7) << 4);
        af[mi] = *(const short8*)((const char*)As + row * 128 + cb);
      }
#pragma unroll
      for (int ni = 0; ni < 4; ni++) {
        int row = wn * 64 + ni * 16 + (lane & 15);
        int cb = (ks * 64 + (lane >> 4) * 16) ^ ((row & 7) << 4);
        bfr[ni] = *(const short8*)((const char*)Bs + row * 128 + cb);
      }
#pragma unroll
      for (int mi = 0; mi < 4; mi++)
#pragma unroll
        for (int ni = 0; ni < 4; ni++)
          acc[mi][ni] = __builtin_amdgcn_mfma_f32_16x16x32_bf16(af[mi], bfr[ni], acc[mi][ni], 0, 0, 0);
    }
    __syncthreads();
  }

  // epilogue: C/D layout col=lane&15, row=(lane>>4)*4+r
  const int c0 = n0 + wn * 64 + (lane & 15);
  const int r0 = m0 + wm * 64 + (lane >> 4) * 4;
#pragma unroll
  for (int mi = 0; mi < 4; mi++)
#pragma unroll
    for (int ni = 0; ni < 4; ni++)
#pragma unroll
      for (int r = 0; r < 4; r++) {
        size_t idx = (size_t)(r0 + mi * 16 + r) * N + (c0 + ni * 16);
        float v = acc[mi][ni][r];
        if constexpr (OUT_F32) ((float*)Cv)[idx] = v;
        else                   ((bf16*)Cv)[idx] = __float2bfloat16(v);
      }
}

// ------------------------- RMSNorm + RoPE + relayout to [B][H][T][HD] bf16
// One wave per (token row m, head-slot). slots: 0..15 Q, 16..23 K, 24..31 V(copy).
__global__ __launch_bounds__(256) void norm_rope(
    const bf16* __restrict__ qkv, const float* __restrict__ qw, const float* __restrict__ kw,
    const float2* __restrict__ tab,
    bf16* __restrict__ Qh, bf16* __restrict__ Kh, bf16* __restrict__ Vh) {
  const int lane = threadIdx.x & 63;
  const int wv_  = threadIdx.x >> 6;
  const int g = blockIdx.x * 4 + wv_;
  const int m = g >> 5, slot = g & 31;
  const int b = m >> 11, t = m & 2047;

  int col, type, h;
  if (slot < 16)      { type = 0; h = slot;      col = h * 128; }
  else if (slot < 24) { type = 1; h = slot - 16; col = 2048 + h * 128; }
  else                { type = 2; h = slot - 24; col = 3072 + h * 128; }

  const bf16* src = qkv + (size_t)m * 4096 + col + lane * 2;
  bf16* dst;
  if (type == 0)      dst = Qh + ((size_t)(b * 16 + h) * 2048 + t) * 128 + lane * 2;
  else if (type == 1) dst = Kh + ((size_t)(b * 8 + h) * 2048 + t) * 128 + lane * 2;
  else                dst = Vh + ((size_t)(b * 8 + h) * 2048 + t) * 128 + lane * 2;

  float x0 = __bfloat162float(src[0]);
  float x1 = __bfloat162float(src[1]);
  if (type == 2) { dst[0] = src[0]; dst[1] = src[1]; return; }  // V: copy only (wave-uniform branch)

  float ss = x0 * x0 + x1 * x1;
#pragma unroll
  for (int o = 1; o < 64; o <<= 1) ss += __shfl_xor(ss, o);
  float rms = sqrtf(ss * (1.f / 128.f));
  float inv = 1.f / (rms + 1e-6f);
  const float* wn = (type == 0) ? qw : kw;
  float n0 = wn[lane * 2] * x0 * inv;
  float n1 = wn[lane * 2 + 1] * x1 * inv;
  float2 cs = tab[t * 64 + lane];
  dst[0] = __float2bfloat16(n0 * cs.x - n1 * cs.y);
  dst[1] = __float2bfloat16(n0 * cs.y + n1 * cs.x);
}

// ------------------------------------------------------- causal GQA flash attention
// Block: 256 thr (4 waves), Q-tile 64 (16 q-rows/wave), KV-tile 64.
__global__ __launch_bounds__(256) void flash_attn(
    const bf16* __restrict__ Qh, const bf16* __restrict__ Kh,
    const bf16* __restrict__ Vh, bf16* __restrict__ Y) {
  __shared__ alignas(16) bf16 Ks[64 * 128];   // [key][hd], 256B rows, swizzled
  __shared__ alignas(16) bf16 Vs[128 * 64];   // transposed [hd][key], 128B rows, swizzled
  __shared__ alignas(16) bf16 Ps[4 * 16 * 64];// per-wave P tile, swizzled
  const int tid = threadIdx.x, lane = tid & 63, w = tid >> 6;
  const int qt = blockIdx.x, bh = blockIdx.y;
  const int b = bh >> 4, h = bh & 15, kvh = h >> 1;  // GQA rep=2
  const bf16* Qg = Qh + ((size_t)(b * 16 + h) * 2048 + qt * 64) * 128;
  const bf16* Kg = Kh + (size_t)(b * 8 + kvh) * 2048 * 128;
  const bf16* Vg = Vh + (size_t)(b * 8 + kvh) * 2048 * 128;

  // Q fragments hoisted to registers (A-frag: row=lane&15, k=8*(lane>>4)+j)
  short8 qf[4];
#pragma unroll
  for (int ks = 0; ks < 4; ks++)
    qf[ks] = *(const short8*)(Qg + (size_t)(w * 16 + (lane & 15)) * 128 + ks * 32 + (lane >> 4) * 8);

  f32x4 o[8] = {};
  float mrow[4], lrow[4];
#pragma unroll
  for (int r = 0; r < 4; r++) { mrow[r] = -1e30f; lrow[r] = 0.f; }

  const int q0 = qt * 64;
  bf16* Pw = Ps + w * 1024;

  for (int kt = 0; kt <= qt; kt++) {
    const int k0 = kt * 64;
    // stage K: linear LDS dest, pre-swizzled global source
#pragma unroll
    for (int i = 0; i < 4; i++) {
      int lin = w * 4096 + i * 1024 + lane * 16;
      int row = lin >> 8, cb = lin & 255;
      int src = cb ^ ((row & 7) << 4);
      async_ld16((const char*)(Kg + (size_t)(k0 + row) * 128) + src,
                 (char*)Ks + w * 4096 + i * 1024);
    }
    // stage V transposed: Vs[hd][key], swizzled writes (2-way conflict = free)
#pragma unroll
    for (int i = 0; i < 4; i++) {
      int g = tid + i * 256;
      int key = g & 63, hd0 = (g >> 6) * 8;
      short8 v = *(const short8*)(Vg + (size_t)(k0 + key) * 128 + hd0);
#pragma unroll
      for (int j = 0; j < 8; j++) {
        int hd = hd0 + j;
        int cb = (key * 2) ^ ((hd & 7) << 4);
        *(bf16*)((char*)Vs + hd * 128 + cb) = ((const bf16*)&v)[j];
      }
    }
    __syncthreads();

    // S = Q . K^T  (B-frag from Ks rows = keys)
    f32x4 s[4] = {};
#pragma unroll
    for (int ni = 0; ni < 4; ni++) {
      int row = ni * 16 + (lane & 15);
#pragma unroll
      for (int ks = 0; ks < 4; ks++) {
        int cb = (ks * 64 + (lane >> 4) * 16) ^ ((row & 7) << 4);
        short8 kf = *(const short8*)((const char*)Ks + row * 256 + cb);
        s[ni] = __builtin_amdgcn_mfma_f32_16x16x32_bf16(qf[ks], kf, s[ni], 0, 0, 0);
      }
    }

    // online softmax (rows owned per-lane: q=(lane>>4)*4+r, reduce over 16 lanes)
    const float scale = 0.08838834764831845f;
    const int qg = q0 + w * 16 + (lane >> 4) * 4;
    float pm[4];
#pragma unroll
    for (int r = 0; r < 4; r++) pm[r] = -1e30f;
#pragma unroll
    for (int ni = 0; ni < 4; ni++) {
      int kg = k0 + ni * 16 + (lane & 15);
#pragma unroll
      for (int r = 0; r < 4; r++) {
        float v = s[ni][r] * scale;
        v = (kg <= qg + r) ? v : -1e30f;  // causal mask
        s[ni][r] = v;
        pm[r] = fmaxf(pm[r], v);
      }
    }
#pragma unroll
    for (int r = 0; r < 4; r++)
#pragma unroll
      for (int off = 1; off < 16; off <<= 1) pm[r] = fmaxf(pm[r], __shfl_xor(pm[r], off));

    float alpha[4], rs[4];
#pragma unroll
    for (int r = 0; r < 4; r++) {
      float mnew = fmaxf(mrow[r], pm[r]);
      alpha[r] = __expf(mrow[r] - mnew);
      mrow[r] = mnew;
      rs[r] = 0.f;
    }
#pragma unroll
    for (int ni = 0; ni < 4; ni++)
#pragma unroll
      for (int r = 0; r < 4; r++) {
        float p = __expf(s[ni][r] - mrow[r]);
        s[ni][r] = p;
        rs[r] += p;
      }
#pragma unroll
    for (int r = 0; r < 4; r++) {
#pragma unroll
      for (int off = 1; off < 16; off <<= 1) rs[r] += __shfl_xor(rs[r], off);
      lrow[r] = lrow[r] * alpha[r] + rs[r];
    }
#pragma unroll
    for (int nf = 0; nf < 8; nf++)
#pragma unroll
      for (int r = 0; r < 4; r++) o[nf][r] *= alpha[r];

    // P -> per-wave LDS tile (bf16, swizzled); no barrier needed (wave-private)
#pragma unroll
    for (int ni = 0; ni < 4; ni++)
#pragma unroll
      for (int r = 0; r < 4; r++) {
        int q = (lane >> 4) * 4 + r;
        int cb = ((ni * 16 + (lane & 15)) * 2) ^ ((q & 7) << 4);
        *(bf16*)((char*)Pw + q * 128 + cb) = __float2bfloat16(s[ni][r]);
      }

    // O += P . V
#pragma unroll
    for (int ks = 0; ks < 2; ks++) {
      int qq = lane & 15;
      int pcb = (ks * 64 + (lane >> 4) * 16) ^ ((qq & 7) << 4);
      short8 pf = *(const short8*)((const char*)Pw + qq * 128 + pcb);
#pragma unroll
      for (int nf = 0; nf < 8; nf++) {
        int row = nf * 16 + (lane & 15);
        int cb = (ks * 64 + (lane >> 4) * 16) ^ ((row & 7) << 4);
        short8 vf = *(const short8*)((const char*)Vs + row * 128 + cb);
        o[nf] = __builtin_amdgcn_mfma_f32_16x16x32_bf16(pf, vf, o[nf], 0, 0, 0);
      }
    }
    __syncthreads();
  }

  // epilogue: Y[b][t][h*128+hd] = O / l   (bf16 for the out-proj GEMM)
#pragma unroll
  for (int nf = 0; nf < 8; nf++)
#pragma unroll
    for (int r = 0; r < 4; r++) {
      int q = (lane >> 4) * 4 + r;
      int t = q0 + w * 16 + q;
      float v = o[nf][r] / lrow[r];
      Y[(size_t)(b * 2048 + t) * 2048 + h * 128 + nf * 16 + (lane & 15)] = __float2bfloat16(v);
    }
}

// ---------------------------------------------------------------- launcher
extern "C" void kernel_launch(void* const* d_in, const int* in_sizes, int n_in,
                              void* d_out, int out_size, void* d_ws, size_t ws_size,
                              hipStream_t stream) {
  (void)in_sizes; (void)n_in; (void)out_size; (void)ws_size;
  const float* x   = (const float*)d_in[0];
  const float* wq  = (const float*)d_in[1];
  const float* wk  = (const float*)d_in[2];
  const float* wv  = (const float*)d_in[3];
  const float* wo  = (const float*)d_in[4];
  const float* qnw = (const float*)d_in[5];
  const float* knw = (const float*)d_in[6];
  float* out = (float*)d_out;
  char* ws = (char*)d_ws;
  const size_t MB = 1u << 20;
  bf16*   xb  = (bf16*)(ws + 0 * MB);    // [4096][1024]
  bf16*   wt  = (bf16*)(ws + 8 * MB);    // [4096][1024]  rows: wq^T | wk^T | wv^T
  bf16*   wot = (bf16*)(ws + 16 * MB);   // [1024][2048]
  bf16*   qkv = (bf16*)(ws + 20 * MB);   // [4096][4096]
  float2* tab = (float2*)(ws + 52 * MB); // [2048][64]
  bf16*   Qh  = (bf16*)(ws + 53 * MB);   // [2][16][2048][128]
  bf16*   Kh  = (bf16*)(ws + 69 * MB);   // [2][8][2048][128]
  bf16*   Vh  = (bf16*)(ws + 77 * MB);   // [2][8][2048][128]
  bf16*   Yb  = (bf16*)(ws + 85 * MB);   // [4096][2048]

  cvt_f32_bf16<<<4096, 256, 0, stream>>>(x, xb, 1048576);
  transpose_cvt<<<dim3(64, 32), 256, 0, stream>>>(wq, wt,               1024, 2048);
  transpose_cvt<<<dim3(32, 32), 256, 0, stream>>>(wk, wt + 2048 * 1024, 1024, 1024);
  transpose_cvt<<<dim3(32, 32), 256, 0, stream>>>(wv, wt + 3072 * 1024, 1024, 1024);
  transpose_cvt<<<dim3(32, 64), 256, 0, stream>>>(wo, wot,              2048, 1024);
  rope_tab<<<2048, 64, 0, stream>>>(tab);
  gemm_bt<false><<<dim3(32, 32), 256, 0, stream>>>(xb, wt, qkv, 4096, 4096, 1024);
  norm_rope<<<32768, 256, 0, stream>>>(qkv, qnw, knw, tab, Qh, Kh, Vh);
  flash_attn<<<dim3(32, 32), 256, 0, stream>>>(Qh, Kh, Vh, Yb);
  gemm_bt<true><<<dim3(8, 32), 256, 0, stream>>>(Yb, wot, out, 4096, 1024, 2048);
}

// Round 2
// 228.078 us; speedup vs baseline: 1.4903x; 1.4903x over previous
//
#include <hip/hip_runtime.h>
#include <hip/hip_bf16.h>
#include <cstdint>
#include <cstddef>

using bf16 = __hip_bfloat16;
using short8 = __attribute__((ext_vector_type(8))) short;
using f32x4  = __attribute__((ext_vector_type(4))) float;

#define DEVI __device__ __forceinline__

// async global->LDS, 16B per lane. LDS dest is wave-uniform base + lane*16.
DEVI void async_ld16(const void* g, void* l) {
  __builtin_amdgcn_global_load_lds(
      (const __attribute__((address_space(1))) unsigned int*)g,
      (__attribute__((address_space(3))) unsigned int*)l, 16, 0, 0);
}

// ---------------------------------------------------------------- cvt f32->bf16
__global__ void cvt_f32_bf16(const float* __restrict__ in, bf16* __restrict__ out, int n4) {
  int i = blockIdx.x * blockDim.x + threadIdx.x;
  if (i >= n4) return;
  float4 v = ((const float4*)in)[i];
  union { bf16 h[4]; ushort4 u; } o;
  o.h[0] = __float2bfloat16(v.x);
  o.h[1] = __float2bfloat16(v.y);
  o.h[2] = __float2bfloat16(v.z);
  o.h[3] = __float2bfloat16(v.w);
  ((ushort4*)out)[i] = o.u;
}

// ------------------------------------------- transpose + cvt: in[K][N] -> out[N][K]
__global__ __launch_bounds__(256) void transpose_cvt(
    const float* __restrict__ in, bf16* __restrict__ out, int K, int N) {
  __shared__ float tile[32][33];
  int n0 = blockIdx.x * 32, k0 = blockIdx.y * 32;
  int tx = threadIdx.x & 31, ty = threadIdx.x >> 5;  // 32 x 8
#pragma unroll
  for (int i = 0; i < 32; i += 8)
    tile[ty + i][tx] = in[(size_t)(k0 + ty + i) * N + n0 + tx];
  __syncthreads();
#pragma unroll
  for (int i = 0; i < 32; i += 8)
    out[(size_t)(n0 + ty + i) * K + k0 + tx] = __float2bfloat16(tile[tx][ty + i]);
}

// ----------------------- V transpose: Vt[b*8+kvh][hd][t] <- qkv[b*2048+t][3072+kvh*128+hd]
__global__ __launch_bounds__(256) void v_transpose(
    const bf16* __restrict__ qkv, bf16* __restrict__ Vt) {
  __shared__ bf16 tile[32][34];
  int bk = blockIdx.z;                       // 0..15
  int t0 = blockIdx.x * 32, h0 = blockIdx.y * 32;
  int tx = threadIdx.x & 31, ty = threadIdx.x >> 5;  // 32 x 8
  int b = bk >> 3, kvh = bk & 7;
  const bf16* src = qkv + (size_t)(b * 2048) * 4096 + 3072 + kvh * 128;
#pragma unroll
  for (int i = 0; i < 32; i += 8)
    tile[ty + i][tx] = src[(size_t)(t0 + ty + i) * 4096 + h0 + tx];
  __syncthreads();
  bf16* dst = Vt + (size_t)bk * 128 * 2048;
#pragma unroll
  for (int i = 0; i < 32; i += 8)
    dst[(size_t)(h0 + ty + i) * 2048 + t0 + tx] = tile[tx][ty + i];
}

// ---------------------------------------------------------------- rope table
__global__ void rope_tab(float2* __restrict__ tab) {
  int t = blockIdx.x, i = threadIdx.x;  // T blocks x 64 threads
  float ex = -2.f * (float)i * (1.f / 128.f);
  float theta = exp2f(ex * 19.9315685693241741f);  // log2(1e6)
  float f = (float)t * theta;
  float sv, cv;
  sincosf(f, &sv, &cv);
  tab[t * 64 + i] = make_float2(cv, sv);
}

// ------------------------------------------------- GEMM: C[M][N] = A[M][K] * Bt[N][K]^T
template <bool OUT_F32>
__global__ __launch_bounds__(256) void gemm_bt(
    const bf16* __restrict__ A, const bf16* __restrict__ Bt,
    void* __restrict__ Cv, int M, int N, int K) {
  __shared__ alignas(16) bf16 As[128 * 64];
  __shared__ alignas(16) bf16 Bs[128 * 64];
  const int tid = threadIdx.x, lane = tid & 63, w = tid >> 6;
  const int wm = w >> 1, wn = w & 1;
  const int m0 = blockIdx.y * 128, n0 = blockIdx.x * 128;
  f32x4 acc[4][4] = {};

  const int srow = lane >> 3;          // row within 8-row slab
  const int scb  = (lane & 7) * 16;    // linear col byte

  for (int kt = 0; kt < K; kt += 64) {
#pragma unroll
    for (int i = 0; i < 4; i++) {
      int row = w * 32 + i * 8 + srow;
      int src_cb = scb ^ ((row & 7) << 4);
      async_ld16((const char*)(A  + (size_t)(m0 + row) * K + kt) + src_cb,
                 (char*)As + w * 4096 + i * 1024);
      async_ld16((const char*)(Bt + (size_t)(n0 + row) * K + kt) + src_cb,
                 (char*)Bs + w * 4096 + i * 1024);
    }
    __syncthreads();
#pragma unroll
    for (int ks = 0; ks < 2; ks++) {
      short8 af[4], bfr[4];
#pragma unroll
      for (int mi = 0; mi < 4; mi++) {
        int row = wm * 64 + mi * 16 + (lane & 15);
        int cb = (ks * 64 + (lane >> 4) * 16) ^ ((row & 7) << 4);
        af[mi] = *(const short8*)((const char*)As + row * 128 + cb);
      }
#pragma unroll
      for (int ni = 0; ni < 4; ni++) {
        int row = wn * 64 + ni * 16 + (lane & 15);
        int cb = (ks * 64 + (lane >> 4) * 16) ^ ((row & 7) << 4);
        bfr[ni] = *(const short8*)((const char*)Bs + row * 128 + cb);
      }
#pragma unroll
      for (int mi = 0; mi < 4; mi++)
#pragma unroll
        for (int ni = 0; ni < 4; ni++)
          acc[mi][ni] = __builtin_amdgcn_mfma_f32_16x16x32_bf16(af[mi], bfr[ni], acc[mi][ni], 0, 0, 0);
    }
    __syncthreads();
  }

  const int c0 = n0 + wn * 64 + (lane & 15);
  const int r0 = m0 + wm * 64 + (lane >> 4) * 4;
#pragma unroll
  for (int mi = 0; mi < 4; mi++)
#pragma unroll
    for (int ni = 0; ni < 4; ni++)
#pragma unroll
      for (int r = 0; r < 4; r++) {
        size_t idx = (size_t)(r0 + mi * 16 + r) * N + (c0 + ni * 16);
        float v = acc[mi][ni][r];
        if constexpr (OUT_F32) ((float*)Cv)[idx] = v;
        else                   ((bf16*)Cv)[idx] = __float2bfloat16(v);
      }
}

// ------------------------- RMSNorm + RoPE + relayout to [B][H][T][HD] bf16 (Q,K only)
__global__ __launch_bounds__(256) void norm_rope(
    const bf16* __restrict__ qkv, const float* __restrict__ qw, const float* __restrict__ kw,
    const float2* __restrict__ tab,
    bf16* __restrict__ Qh, bf16* __restrict__ Kh) {
  const int lane = threadIdx.x & 63;
  const int slot = blockIdx.x * 4 + (threadIdx.x >> 6);  // 0..23
  const int m = blockIdx.y;
  const int b = m >> 11, t = m & 2047;

  int type = slot < 16 ? 0 : 1;
  int h = type ? slot - 16 : slot;
  int col = type ? 2048 + h * 128 : h * 128;

  const bf16* src = qkv + (size_t)m * 4096 + col + lane * 2;
  bf16* dst = type
      ? Kh + ((size_t)(b * 8 + h) * 2048 + t) * 128 + lane * 2
      : Qh + ((size_t)(b * 16 + h) * 2048 + t) * 128 + lane * 2;

  float x0 = __bfloat162float(src[0]);
  float x1 = __bfloat162float(src[1]);

  float ss = x0 * x0 + x1 * x1;
#pragma unroll
  for (int o = 1; o < 64; o <<= 1) ss += __shfl_xor(ss, o);
  float rms = sqrtf(ss * (1.f / 128.f));
  float inv = 1.f / (rms + 1e-6f);
  const float* wn = type ? kw : qw;
  float n0 = wn[lane * 2] * x0 * inv;
  float n1 = wn[lane * 2 + 1] * x1 * inv;
  float2 cs = tab[t * 64 + lane];
  dst[0] = __float2bfloat16(n0 * cs.x - n1 * cs.y);
  dst[1] = __float2bfloat16(n0 * cs.y + n1 * cs.x);
}

// ------------------------------------------------------- causal GQA flash attention v2
// 256 thr (4 waves). Block owns q-tile pair {p, 31-p} (64 rows each) => 33 kv-steps/block.
// Double-buffered K/V staging via global_load_lds, 2-phase pipeline, 1 barrier/step.
__global__ __launch_bounds__(256) void flash_attn2(
    const bf16* __restrict__ Qh, const bf16* __restrict__ Kh,
    const bf16* __restrict__ Vt, bf16* __restrict__ Y) {
  __shared__ alignas(16) bf16 Ks[2][64 * 128];   // [key][hd] rows 256B, swizzled
  __shared__ alignas(16) bf16 Vs[2][128 * 64];   // [hd][key] rows 128B, swizzled
  __shared__ alignas(16) bf16 Ps[4][16 * 64];    // per-wave P tile, swizzled
  const int tid = threadIdx.x, lane = tid & 63, w = tid >> 6;

  // bijective XCD swizzle: 512 wgs -> each XCD owns 64 consecutive (4 bh groups)
  int orig = blockIdx.x;
  int wg = (orig & 7) * 64 + (orig >> 3);
  const int p = wg & 15, bh = wg >> 4;
  const int b = bh >> 4, h = bh & 15, kvh = h >> 1;

  const bf16* Qg = Qh + (size_t)(b * 16 + h) * 2048 * 128;
  const bf16* Kg = Kh + (size_t)(b * 8 + kvh) * 2048 * 128;
  const bf16* Vg = Vt + (size_t)(b * 8 + kvh) * 128 * 2048;
  bf16* Pw = Ps[w];

  const int qtA = p, qtB = 31 - p;
  const int nA = qtA + 1;
  const int total = 33;  // nA + (32 - qtA)

  short8 qf[4];
  f32x4 o[8];
  float mrow[4], lrow[4];

  auto loadQ = [&](int qt) {
#pragma unroll
    for (int ks = 0; ks < 4; ks++)
      qf[ks] = *(const short8*)(Qg + (size_t)(qt * 64 + w * 16 + (lane & 15)) * 128 +
                                ks * 32 + (lane >> 4) * 8);
  };
  auto resetState = [&]() {
#pragma unroll
    for (int nf = 0; nf < 8; nf++) o[nf] = f32x4{0.f, 0.f, 0.f, 0.f};
#pragma unroll
    for (int r = 0; r < 4; r++) { mrow[r] = -1e30f; lrow[r] = 0.f; }
  };
  auto stage = [&](int buf, int k0) {
    // K tile: 64 rows x 256B
#pragma unroll
    for (int i = 0; i < 4; i++) {
      int row = w * 16 + i * 4 + (lane >> 4);
      int cb = ((lane & 15) * 16) ^ ((row & 7) << 4);
      async_ld16((const char*)(Kg + (size_t)(k0 + row) * 128) + cb,
                 (char*)Ks[buf] + w * 4096 + i * 1024);
    }
    // V tile: 128 rows x 128B from Vt rows
#pragma unroll
    for (int i = 0; i < 4; i++) {
      int row = w * 32 + i * 8 + (lane >> 3);
      int cb = ((lane & 7) * 16) ^ ((row & 7) << 4);
      async_ld16((const char*)(Vg + (size_t)row * 2048 + k0) + cb,
                 (char*)Vs[buf] + w * 4096 + i * 1024);
    }
  };
  auto epilogue = [&](int qt) {
#pragma unroll
    for (int nf = 0; nf < 8; nf++)
#pragma unroll
      for (int r = 0; r < 4; r++) {
        int q = (lane >> 4) * 4 + r;
        int t = qt * 64 + w * 16 + q;
        float v = o[nf][r] / lrow[r];
        Y[(size_t)(b * 2048 + t) * 2048 + h * 128 + nf * 16 + (lane & 15)] =
            __float2bfloat16(v);
      }
  };
  auto computeStep = [&](int buf, int qt, int kt) {
    // S = Q . K^T
    f32x4 sv[4] = {};
#pragma unroll
    for (int ni = 0; ni < 4; ni++) {
      int row = ni * 16 + (lane & 15);
#pragma unroll
      for (int ks = 0; ks < 4; ks++) {
        int cb = (ks * 64 + (lane >> 4) * 16) ^ ((row & 7) << 4);
        short8 kf = *(const short8*)((const char*)Ks[buf] + row * 256 + cb);
        sv[ni] = __builtin_amdgcn_mfma_f32_16x16x32_bf16(qf[ks], kf, sv[ni], 0, 0, 0);
      }
    }
    // scale into log2 domain; mask only on diagonal tile
    const float sc = 0.12751744416163417f;  // (1/sqrt(128)) * log2(e)
    float pm[4] = {-1e30f, -1e30f, -1e30f, -1e30f};
    if (kt == qt) {
      const int qg = qt * 64 + w * 16 + (lane >> 4) * 4;
#pragma unroll
      for (int ni = 0; ni < 4; ni++) {
        int kg = kt * 64 + ni * 16 + (lane & 15);
#pragma unroll
        for (int r = 0; r < 4; r++) {
          float v = sv[ni][r] * sc;
          v = (kg <= qg + r) ? v : -1e30f;
          sv[ni][r] = v;
          pm[r] = fmaxf(pm[r], v);
        }
      }
    } else {
#pragma unroll
      for (int ni = 0; ni < 4; ni++)
#pragma unroll
        for (int r = 0; r < 4; r++) {
          float v = sv[ni][r] * sc;
          sv[ni][r] = v;
          pm[r] = fmaxf(pm[r], v);
        }
    }
#pragma unroll
    for (int r = 0; r < 4; r++)
#pragma unroll
      for (int off = 1; off < 16; off <<= 1) pm[r] = fmaxf(pm[r], __shfl_xor(pm[r], off));

    float alpha[4], rs[4];
#pragma unroll
    for (int r = 0; r < 4; r++) {
      float mnew = fmaxf(mrow[r], pm[r]);
      alpha[r] = exp2f(mrow[r] - mnew);
      mrow[r] = mnew;
      rs[r] = 0.f;
    }
#pragma unroll
    for (int ni = 0; ni < 4; ni++)
#pragma unroll
      for (int r = 0; r < 4; r++) {
        float pv = exp2f(sv[ni][r] - mrow[r]);
        sv[ni][r] = pv;
        rs[r] += pv;
      }
#pragma unroll
    for (int r = 0; r < 4; r++) {
#pragma unroll
      for (int off = 1; off < 16; off <<= 1) rs[r] += __shfl_xor(rs[r], off);
      lrow[r] = lrow[r] * alpha[r] + rs[r];
    }
#pragma unroll
    for (int nf = 0; nf < 8; nf++)
#pragma unroll
      for (int r = 0; r < 4; r++) o[nf][r] *= alpha[r];

    // P -> per-wave LDS tile (bf16, swizzled); wave-private, no barrier
#pragma unroll
    for (int ni = 0; ni < 4; ni++)
#pragma unroll
      for (int r = 0; r < 4; r++) {
        int q = (lane >> 4) * 4 + r;
        int cb = ((ni * 16 + (lane & 15)) * 2) ^ ((q & 7) << 4);
        *(bf16*)((char*)Pw + q * 128 + cb) = __float2bfloat16(sv[ni][r]);
      }

    // O += P . V
#pragma unroll
    for (int ks = 0; ks < 2; ks++) {
      int qq = lane & 15;
      int pcb = (ks * 64 + (lane >> 4) * 16) ^ ((qq & 7) << 4);
      short8 pf = *(const short8*)((const char*)Pw + qq * 128 + pcb);
#pragma unroll
      for (int nf = 0; nf < 8; nf++) {
        int row = nf * 16 + (lane & 15);
        int cb = (ks * 64 + (lane >> 4) * 16) ^ ((row & 7) << 4);
        short8 vf = *(const short8*)((const char*)Vs[buf] + row * 128 + cb);
        o[nf] = __builtin_amdgcn_mfma_f32_16x16x32_bf16(pf, vf, o[nf], 0, 0, 0);
      }
    }
  };

  loadQ(qtA);
  resetState();
  stage(0, 0);
  __syncthreads();

  for (int s = 0; s < total; ++s) {
    if (s + 1 < total) {
      int s1 = s + 1;
      int k1 = (s1 < nA ? s1 : s1 - nA) * 64;
      stage(s1 & 1, k1);
    }
    if (s == nA) {  // tile switch: finish A, start B
      epilogue(qtA);
      loadQ(qtB);
      resetState();
    }
    int qt = (s < nA) ? qtA : qtB;
    int kt = (s < nA) ? s : s - nA;
    computeStep(s & 1, qt, kt);
    __syncthreads();
  }
  epilogue(qtB);
}

// ---------------------------------------------------------------- launcher
extern "C" void kernel_launch(void* const* d_in, const int* in_sizes, int n_in,
                              void* d_out, int out_size, void* d_ws, size_t ws_size,
                              hipStream_t stream) {
  (void)in_sizes; (void)n_in; (void)out_size; (void)ws_size;
  const float* x   = (const float*)d_in[0];
  const float* wq  = (const float*)d_in[1];
  const float* wk  = (const float*)d_in[2];
  const float* wv  = (const float*)d_in[3];
  const float* wo  = (const float*)d_in[4];
  const float* qnw = (const float*)d_in[5];
  const float* knw = (const float*)d_in[6];
  float* out = (float*)d_out;
  char* ws = (char*)d_ws;
  const size_t MB = 1u << 20;
  bf16*   xb  = (bf16*)(ws + 0 * MB);    // [4096][1024]
  bf16*   wt  = (bf16*)(ws + 8 * MB);    // [4096][1024]  rows: wq^T | wk^T | wv^T
  bf16*   wot = (bf16*)(ws + 16 * MB);   // [1024][2048]
  bf16*   qkv = (bf16*)(ws + 20 * MB);   // [4096][4096]
  float2* tab = (float2*)(ws + 52 * MB); // [2048][64]
  bf16*   Qh  = (bf16*)(ws + 53 * MB);   // [2][16][2048][128]
  bf16*   Kh  = (bf16*)(ws + 69 * MB);   // [2][8][2048][128]
  bf16*   Vtr = (bf16*)(ws + 77 * MB);   // [2][8][128][2048]  (V transposed)
  bf16*   Yb  = (bf16*)(ws + 85 * MB);   // [4096][2048]

  cvt_f32_bf16<<<4096, 256, 0, stream>>>(x, xb, 1048576);
  transpose_cvt<<<dim3(64, 32), 256, 0, stream>>>(wq, wt,               1024, 2048);
  transpose_cvt<<<dim3(32, 32), 256, 0, stream>>>(wk, wt + 2048 * 1024, 1024, 1024);
  transpose_cvt<<<dim3(32, 32), 256, 0, stream>>>(wv, wt + 3072 * 1024, 1024, 1024);
  transpose_cvt<<<dim3(32, 64), 256, 0, stream>>>(wo, wot,              2048, 1024);
  rope_tab<<<2048, 64, 0, stream>>>(tab);
  gemm_bt<false><<<dim3(32, 32), 256, 0, stream>>>(xb, wt, qkv, 4096, 4096, 1024);
  norm_rope<<<dim3(6, 4096), 256, 0, stream>>>(qkv, qnw, knw, tab, Qh, Kh);
  v_transpose<<<dim3(64, 4, 16), 256, 0, stream>>>(qkv, Vtr);
  flash_attn2<<<512, 256, 0, stream>>>(Qh, Kh, Vtr, Yb);
  gemm_bt<true><<<dim3(8, 32), 256, 0, stream>>>(Yb, wot, out, 4096, 1024, 2048);
}